// Round 1
// baseline (22.081 us; speedup 1.0000x reference)
//
#include <hip/hip_runtime.h>
#include <math.h>

#define NN 1024
#define HH 512
#define BB 64

__global__ __launch_bounds__(1024) void lfl_main(const float* __restrict__ scores,
                                                 const float* __restrict__ labels,
                                                 float* __restrict__ partial) {
    __shared__ float key[NN];
    __shared__ float val[NN];
    __shared__ float sa[NN];
    __shared__ float sb[NN];
    __shared__ float wsum[16];

    const int b   = blockIdx.x;
    const int tid = threadIdx.x;

    // Load: sort key = -label (ascending on -label == descending label == argsort(-labels))
    key[tid] = -labels[b * NN + tid];
    val[tid] = scores[b * NN + tid];   // scores shape (B,N,1) -> same flat layout
    __syncthreads();

    // Bitonic sort (ascending on key), payload = val
    for (unsigned size = 2; size <= NN; size <<= 1) {
        for (unsigned stride = size >> 1; stride > 0; stride >>= 1) {
            unsigned i = tid;
            unsigned l = i ^ stride;
            if (l > i) {
                float ki = key[i], kl = key[l];
                bool up = ((i & size) == 0u);
                if ((ki > kl) == up) {
                    key[i] = kl; key[l] = ki;
                    float vi = val[i], vl = val[l];
                    val[i] = vl; val[l] = vi;
                }
            }
            __syncthreads();
        }
    }

    // osc = sorted scores; build exp arrays for suffix scans
    float osc = val[tid];
    sa[tid] = expf(osc);    // e^{osc[n]}
    sb[tid] = expf(-osc);   // e^{-osc[k]}
    __syncthreads();

    // Inclusive SUFFIX scan (Hillis-Steele): sa[i] = sum_{n>=i} e^{osc[n]}, same for sb
    for (int d = 1; d < NN; d <<= 1) {
        float ta = (tid + d < NN) ? sa[tid + d] : 0.0f;
        float tb = (tid + d < NN) ? sb[tid + d] : 0.0f;
        __syncthreads();
        sa[tid] += ta;
        sb[tid] += tb;
        __syncthreads();
    }

    // Per-j loss term, j in [0, H)
    float term = 0.0f;
    if (tid < HH) {
        int j = tid;
        float P = sa[j] - sa[HH + 1];        // sum_{n=j}^{512} e^{osc[n]}
        float T = sb[HH - 1 + j];            // sum_{k=511+j}^{1023} e^{-osc[k]}
        float denom = P * T - (j == 0 ? 2.0f : (j == 1 ? 1.0f : 0.0f));
        // log numer = osc[j] - osc[N-1-j]
        term = (val[j] - val[NN - 1 - j]) - logf(denom);
    }

    // Block reduction: wave shuffle then cross-wave via LDS
    for (int off = 32; off > 0; off >>= 1) term += __shfl_down(term, off);
    int wave = tid >> 6, lane = tid & 63;
    if (lane == 0) wsum[wave] = term;
    __syncthreads();
    if (tid == 0) {
        float s = 0.0f;
        #pragma unroll
        for (int w = 0; w < 16; ++w) s += wsum[w];
        partial[b] = s;
    }
}

__global__ __launch_bounds__(64) void lfl_final(const float* __restrict__ partial,
                                                float* __restrict__ out) {
    int tid = threadIdx.x;
    float v = (tid < BB) ? partial[tid] : 0.0f;
    for (int off = 32; off > 0; off >>= 1) v += __shfl_down(v, off);
    if (tid == 0) out[0] = -v / (float)BB;
}

extern "C" void kernel_launch(void* const* d_in, const int* in_sizes, int n_in,
                              void* d_out, int out_size, void* d_ws, size_t ws_size,
                              hipStream_t stream) {
    const float* scores = (const float*)d_in[0];
    const float* labels = (const float*)d_in[1];
    float* out = (float*)d_out;
    float* partial = (float*)d_ws;

    lfl_main<<<BB, NN, 0, stream>>>(scores, labels, partial);
    lfl_final<<<1, 64, 0, stream>>>(partial, out);
}

// Round 2
// 19.750 us; speedup vs baseline: 1.1180x; 1.1180x over previous
//
#include <hip/hip_runtime.h>
#include <math.h>

#define NN 1024
#define HH 512
#define BB 64

__global__ __launch_bounds__(1024) void lfl_fused(const float* __restrict__ scores,
                                                  const float* __restrict__ labels,
                                                  float* __restrict__ out) {
    __shared__ float kL[NN];
    __shared__ float vL[NN];
    __shared__ float wA[16];
    __shared__ float wB[16];
    __shared__ float sa513s;

    const int b    = blockIdx.x;
    const int tid  = threadIdx.x;
    const int lane = tid & 63;
    const int wave = tid >> 6;

    // key = -label (ascending sort == descending label == argsort(-labels)), payload = score
    float k = -labels[b * NN + tid];
    float v = scores[b * NN + tid];

    // ---- Bitonic sort: sizes 2..64 entirely intra-wave (shuffles, no barriers) ----
    #pragma unroll
    for (unsigned size = 2; size <= 64; size <<= 1) {
        bool up = ((tid & size) == 0u);
        #pragma unroll
        for (unsigned stride = size >> 1; stride >= 1; stride >>= 1) {
            float kp = __shfl_xor(k, (int)stride);
            float vp = __shfl_xor(v, (int)stride);
            bool lower = ((tid & stride) == 0u);
            bool take = (up == lower) ? (kp < k) : (kp > k);   // tie -> no swap (no duplication)
            if (take) { k = kp; v = vp; }
        }
    }

    // ---- Sizes 128..1024: strides >=64 via LDS exchange, rest via shuffles ----
    #pragma unroll
    for (unsigned size = 128; size <= 1024; size <<= 1) {
        bool up = ((tid & size) == 0u);
        for (unsigned stride = size >> 1; stride >= 64; stride >>= 1) {
            kL[tid] = k; vL[tid] = v;
            __syncthreads();
            unsigned p = tid ^ stride;
            float kp = kL[p];
            float vp = vL[p];
            bool lower = ((tid & stride) == 0u);
            bool take = (up == lower) ? (kp < k) : (kp > k);
            if (take) { k = kp; v = vp; }
            __syncthreads();
        }
        #pragma unroll
        for (unsigned stride = 32; stride >= 1; stride >>= 1) {
            float kp = __shfl_xor(k, (int)stride);
            float vp = __shfl_xor(v, (int)stride);
            bool lower = ((tid & stride) == 0u);
            bool take = (up == lower) ? (kp < k) : (kp > k);
            if (take) { k = kp; v = vp; }
        }
    }

    // thread tid now holds sorted element tid: osc[tid] = v

    // ---- Suffix scans of e^{osc} and e^{-osc}, in-register per wave ----
    float sa = expf(v);
    float sb = expf(-v);
    #pragma unroll
    for (int d = 1; d < 64; d <<= 1) {
        float ta = __shfl_down(sa, d);
        float tb = __shfl_down(sb, d);
        if (lane + d < 64) { sa += ta; sb += tb; }
    }
    // cross-wave fixup: add totals of all waves above mine
    if (lane == 0) { wA[wave] = sa; wB[wave] = sb; }
    __syncthreads();
    for (int w = wave + 1; w < 16; ++w) { sa += wA[w]; sb += wB[w]; }

    // ---- Publish what the term computation needs at foreign indices ----
    vL[tid] = v;        // osc values (need osc[1023-j])
    kL[tid] = sb;       // suffix of e^{-osc} (need index 511+j)
    if (tid == HH + 1) sa513s = sa;   // sa[513], broadcast scalar
    __syncthreads();

    // ---- Per-j term, j = tid < 512 ----
    float term = 0.0f;
    if (tid < HH) {
        float P = sa - sa513s;                 // sum_{n=j}^{512} e^{osc[n]}
        float T = kL[HH - 1 + tid];            // sum_{k=511+j}^{1023} e^{-osc[k]}
        float denom = P * T - (tid == 0 ? 2.0f : (tid == 1 ? 1.0f : 0.0f));
        term = (v - vL[NN - 1 - tid]) - logf(denom);
    }

    // ---- Block reduction + single atomic into out ----
    #pragma unroll
    for (int off = 32; off > 0; off >>= 1) term += __shfl_down(term, off);
    if (lane == 0) wA[wave] = term;            // safe: separated from reads by barrier above
    __syncthreads();
    if (tid == 0) {
        float s = 0.0f;
        #pragma unroll
        for (int w = 0; w < 16; ++w) s += wA[w];
        atomicAdd(out, -s / (float)BB);
    }
}

extern "C" void kernel_launch(void* const* d_in, const int* in_sizes, int n_in,
                              void* d_out, int out_size, void* d_ws, size_t ws_size,
                              hipStream_t stream) {
    const float* scores = (const float*)d_in[0];
    const float* labels = (const float*)d_in[1];
    float* out = (float*)d_out;

    hipMemsetAsync(out, 0, sizeof(float), stream);
    lfl_fused<<<BB, NN, 0, stream>>>(scores, labels, out);
}